// Round 13
// baseline (232.881 us; speedup 1.0000x reference)
//
#include <hip/hip_runtime.h>
#include <cstdint>
#include <cstddef>

// MultiHeadAttention: B=4, S=2048, D=768, H=16, Dh=48, fp32 I/O.
// bf16 MFMA: cvt_w -> fused QKV GEMM (f32-A fused cvt) -> in-block split-K
// flash-attn -> out GEMM.
// v18: kill the x-conversion round-trip. cvt_all's x-portion (6144 of 8448
// blocks) + xb 25MB HBM round-trip removed; gemm_qkv stages A directly from
// f32 x: prologue f32 loads -> per-iter packbf x4 + ds_write_b128 (T14
// issue-early/write-late: next iter's f32 loads issue under current MFMA).
// BIT-IDENTICAL: packbf(a,b) = {f2b(a),f2b(b)} = cvt_all's conversion; LDS
// image layout unchanged. Weights still cvt'd once (cvt_w, 2304 blocks).
// Carried: XCD swizzle all kernels, BK=64 GEMMs, gemm_out 64x128 (3.0/CU,
// zero tail), in-block split-K attn + setprio (77.9us), packbf,
// permlane32_swap, dh-pad skip, xor-swizzled frags.

typedef short s8v __attribute__((ext_vector_type(8)));    // 8 x bf16 (4 VGPRs)
typedef float f4v __attribute__((ext_vector_type(4)));    // 16x16 accumulator
typedef float f16v __attribute__((ext_vector_type(16)));  // 32x32 accumulator

static constexpr int Bn = 4, Sn = 2048, Dn = 768, Hn = 16, DhN = 48, Dp = 64;
static constexpr int MS = Bn * Sn;  // 8192 rows

#define MFMA16(a, b, c) __builtin_amdgcn_mfma_f32_16x16x32_bf16((a), (b), (c), 0, 0, 0)
#define MFMA32(a, b, c) __builtin_amdgcn_mfma_f32_32x32x16_bf16((a), (b), (c), 0, 0, 0)

__device__ __forceinline__ int swz4(int r) { return (r + (r >> 2)) & 3; }

__device__ __forceinline__ ushort f2b(float f) {
  return (ushort)((__builtin_bit_cast(uint32_t, f) + 0x8000u) >> 16);
}
// pack hi16(a+0x8000), hi16(b+0x8000) via v_perm_b32 (a -> low half)
__device__ __forceinline__ uint32_t packbf(float a, float b) {
  uint32_t ua = __builtin_bit_cast(uint32_t, a) + 0x8000u;
  uint32_t ub = __builtin_bit_cast(uint32_t, b) + 0x8000u;
  return __builtin_amdgcn_perm(ub, ua, 0x07060302u);
}
// swap upper 32 lanes of a with lower 32 lanes of b (in place, both usable)
__device__ __forceinline__ void pl32swap(uint32_t& a, uint32_t& b) {
  asm("v_permlane32_swap_b32 %0, %1" : "+v"(a), "+v"(b));
}
__device__ __forceinline__ float fexp2(float x) {
  return __builtin_amdgcn_exp2f(x);
}
__device__ __forceinline__ void gload_lds16(const ushort* g, ushort* l) {
  __builtin_amdgcn_global_load_lds(
      (const __attribute__((address_space(1))) uint32_t*)g,
      (__attribute__((address_space(3))) uint32_t*)l, 16, 0, 0);
}

// Convert the 4 weight matrices to bf16 (x is consumed f32 by gemm_qkv now).
__global__ void cvt_w(const float* __restrict__ wq, const float* __restrict__ wk,
                      const float* __restrict__ wv, const float* __restrict__ wo,
                      ushort* __restrict__ wqkv, ushort* __restrict__ wob) {
  const int bid = blockIdx.x;
  const int r = bid / 576;
  const int i = (bid % 576) * 256 + threadIdx.x;
  const float* src = (r == 0) ? wq : (r == 1) ? wk : (r == 2) ? wv : wo;
  ushort* dst = (r < 3) ? (wqkv + (size_t)r * Dn * Dn) : wob;
  float4 f = ((const float4*)src)[i];
  ushort4 o = { f2b(f.x), f2b(f.y), f2b(f.z), f2b(f.w) };
  ((ushort4*)dst)[i] = o;
}

// ---- Fused QKV GEMM (A = x in f32, fused convert; B = W bf16). Swizzled LDS.
// BK=64: 12 K-iters. A-side: reg-staged f32 -> packbf -> ds_write_b128
// (prefetch next iter's f32 under compute). B-side: gload_lds.
// XCD swizzle: nwg=1152, XCD c gets 144 consecutive cells.
__global__ __launch_bounds__(256) void gemm_qkv(
    const float* __restrict__ X, const ushort* __restrict__ W,
    const float* __restrict__ bq, const float* __restrict__ bk, const float* __restrict__ bv,
    ushort* __restrict__ outq, ushort* __restrict__ outk, ushort* __restrict__ outv,
    float qscale) {
  __shared__ __align__(16) ushort As[128][64];   // x rows (bf16 image)
  __shared__ __align__(16) ushort Bs[128][64];   // W rows
  const int tid = threadIdx.x, lane = tid & 63, wave = tid >> 6;
  const int l15 = lane & 15, g = lane >> 4;
  // XCD-aware bijective relabel: hw round-robins linear id % 8 across XCDs.
  const int lin0 = blockIdx.x + blockIdx.y * 18;        // 0..1151
  const int lin = (lin0 & 7) * 144 + (lin0 >> 3);       // XCD-chunked, bijective
  const int nx = lin % 18, my = lin / 18;
  const int m0 = my * 128, n0 = nx * 128;
  const int wqm = (wave >> 1) * 64;   // weight-dim quadrant
  const int wqx = (wave & 1) * 64;    // x-dim quadrant
  f4v acc[4][4] = {};                 // [i=wtile][j=xtile]

  const float* axp[4];
  const ushort* bgp[4];
  ushort* lap[4];
  ushort* lbp[4];
#pragma unroll
  for (int q = 0; q < 4; ++q) {
    const int slot = q * 256 + wave * 64 + lane;   // 0..1023
    const int r = slot >> 3, sc = slot & 7;
    const int u = ((((sc & 3) ^ swz4(r & 15)) | (sc & 4)) ^ ((r & 1) << 2)) * 8;
    axp[q] = X + (size_t)(m0 + r) * Dn + u;
    bgp[q] = W + (size_t)(n0 + r) * Dn + u;
    lap[q] = &As[0][0] + slot * 8;
    lbp[q] = &Bs[0][0] + slot * 8;
  }
  const int fcol = (g ^ swz4(l15)) * 8;
  const int par = l15 & 1;

  // prologue: stage k0=0 A-chunk into registers (f32)
  float4 ar[4][2];
#pragma unroll
  for (int q = 0; q < 4; ++q) {
    ar[q][0] = *(const float4*)(axp[q]);
    ar[q][1] = *(const float4*)(axp[q] + 4);
  }

  for (int k0 = 0; k0 < Dn; k0 += 64) {
    __syncthreads();
#pragma unroll
    for (int q = 0; q < 4; ++q) gload_lds16(bgp[q] + k0, lbp[q]);
    // convert + LDS write (bit-identical to cvt_all's f2b image)
#pragma unroll
    for (int q = 0; q < 4; ++q) {
      uint4 w;
      w.x = packbf(ar[q][0].x, ar[q][0].y);
      w.y = packbf(ar[q][0].z, ar[q][0].w);
      w.z = packbf(ar[q][1].x, ar[q][1].y);
      w.w = packbf(ar[q][1].z, ar[q][1].w);
      *(uint4*)lap[q] = w;
    }
    // issue next iter's f32 loads; latency hides under this iter's MFMA
    if (k0 + 64 < Dn) {
#pragma unroll
      for (int q = 0; q < 4; ++q) {
        ar[q][0] = *(const float4*)(axp[q] + k0 + 64);
        ar[q][1] = *(const float4*)(axp[q] + k0 + 68);
      }
    }
    __syncthreads();
#pragma unroll
    for (int h = 0; h < 2; ++h) {
      const int fc = fcol + 32 * (h ^ par);   // holds global k-substep h
      s8v wf[4], xf[4];
#pragma unroll
      for (int i = 0; i < 4; ++i) wf[i] = *(const s8v*)&Bs[wqm + i * 16 + l15][fc];
#pragma unroll
      for (int j = 0; j < 4; ++j) xf[j] = *(const s8v*)&As[wqx + j * 16 + l15][fc];
#pragma unroll
      for (int i = 0; i < 4; ++i)
#pragma unroll
        for (int j = 0; j < 4; ++j) acc[i][j] = MFMA16(wf[i], xf[j], acc[i][j]);
    }
  }

  const int region = nx / 6;                // uniform per block
  const int nbase = n0 - region * 768;
  const float* bias = (region == 0) ? bq : (region == 1) ? bk : bv;
#pragma unroll
  for (int i = 0; i < 4; ++i) {
    const int n = nbase + wqm + i * 16 + g * 4;   // 4 consecutive n, same head
    const float4 b4 = *(const float4*)&bias[n];
    const int h = n / DhN, dh = n - h * DhN;
#pragma unroll
    for (int j = 0; j < 4; ++j) {
      const int s = m0 + wqx + j * 16 + l15;
      const int b = s >> 11, srow = s & 2047;
      const int bh = b * Hn + h;
      float v0 = acc[i][j][0] + b4.x, v1 = acc[i][j][1] + b4.y;
      float v2 = acc[i][j][2] + b4.z, v3 = acc[i][j][3] + b4.w;
      if (region == 0) { v0 *= qscale; v1 *= qscale; v2 *= qscale; v3 *= qscale; }
      if (region < 2) {
        ushort4 o = { f2b(v0), f2b(v1), f2b(v2), f2b(v3) };
        ushort* dst = region ? outk : outq;
        *(ushort4*)&dst[((size_t)bh * Sn + srow) * Dp + dh] = o;
      } else {
        outv[((size_t)bh * DhN + dh + 0) * Sn + srow] = f2b(v0);
        outv[((size_t)bh * DhN + dh + 1) * Sn + srow] = f2b(v1);
        outv[((size_t)bh * DhN + dh + 2) * Sn + srow] = f2b(v2);
        outv[((size_t)bh * DhN + dh + 3) * Sn + srow] = f2b(v3);
      }
    }
  }
}

// ---- Out projection GEMM (swapped operands, float4 stores). BK=64.
// 64x128 tile; grid 768 = 3.0 blocks/CU, zero tail. XCD swizzle chunk=96.
__global__ __launch_bounds__(256) void gemm_out(
    const ushort* __restrict__ A, const ushort* __restrict__ W,
    const float* __restrict__ bias, float* __restrict__ out) {
  __shared__ __align__(16) ushort As[64][64];
  __shared__ __align__(16) ushort Bs[128][64];
  const int tid = threadIdx.x, lane = tid & 63, wave = tid >> 6;
  const int l15 = lane & 15, g = lane >> 4;
  const int lin0 = blockIdx.x + blockIdx.y * 6;         // 0..767
  const int lin = (lin0 & 7) * 96 + (lin0 >> 3);        // XCD-chunked, bijective
  const int nx = lin % 6, my = lin / 6;
  const int m0 = my * 64, n0 = nx * 128;
  const int wqm = (wave >> 1) * 64;   // n-quadrant (0/64)
  const int wqx = (wave & 1) * 32;    // m-quadrant (0/32)
  f4v acc[4][2] = {};                 // [i=n-tile][j=m-tile]

  const ushort* agp[2];
  const ushort* bgp[4];
  ushort* lap[2];
  ushort* lbp[4];
#pragma unroll
  for (int q = 0; q < 4; ++q) {
    const int slot = q * 256 + wave * 64 + lane;   // 0..1023
    const int r = slot >> 3, sc = slot & 7;
    const int u = ((((sc & 3) ^ swz4(r & 15)) | (sc & 4)) ^ ((r & 1) << 2)) * 8;
    bgp[q] = W + (size_t)(n0 + r) * Dn + u;
    lbp[q] = &Bs[0][0] + slot * 8;
    if (q < 2) {
      agp[q] = A + (size_t)(m0 + r) * Dn + u;
      lap[q] = &As[0][0] + slot * 8;
    }
  }
  const int fcol = (g ^ swz4(l15)) * 8;
  const int par = l15 & 1;

  for (int k0 = 0; k0 < Dn; k0 += 64) {
    __syncthreads();
#pragma unroll
    for (int q = 0; q < 4; ++q) gload_lds16(bgp[q] + k0, lbp[q]);
#pragma unroll
    for (int q = 0; q < 2; ++q) gload_lds16(agp[q] + k0, lap[q]);
    __syncthreads();
#pragma unroll
    for (int h = 0; h < 2; ++h) {
      const int fc = fcol + 32 * (h ^ par);
      s8v wf[4], xf[2];
#pragma unroll
      for (int i = 0; i < 4; ++i) wf[i] = *(const s8v*)&Bs[wqm + i * 16 + l15][fc];
#pragma unroll
      for (int j = 0; j < 2; ++j) xf[j] = *(const s8v*)&As[wqx + j * 16 + l15][fc];
#pragma unroll
      for (int i = 0; i < 4; ++i)
#pragma unroll
        for (int j = 0; j < 2; ++j) acc[i][j] = MFMA16(wf[i], xf[j], acc[i][j]);
    }
  }

#pragma unroll
  for (int i = 0; i < 4; ++i) {
    const int n = n0 + wqm + i * 16 + g * 4;
    const float4 b4 = *(const float4*)&bias[n];
#pragma unroll
    for (int j = 0; j < 2; ++j) {
      const int s = m0 + wqx + j * 16 + l15;
      float4 o4 = { acc[i][j][0] + b4.x, acc[i][j][1] + b4.y,
                    acc[i][j][2] + b4.z, acc[i][j][3] + b4.w };
      *(float4*)&out[(size_t)s * Dn + n] = o4;
    }
  }
}

// ---- In-block split-K flash attention (v17, passing, verbatim). grid (16, 64),
// block 512 (8 waves = 2 key-groups x 4 q-waves of 32 q each). Group g: keys
// [1024g, 1024g+1024), 16 x 64-key tiles in its own LDS half (14KB).
// Epilogue: group 1 -> LDS scratch (transposed, conflict-free), group 0 adds
// + normalizes (lsum = dh48 ones-row col). setprio around MFMA clusters.
__global__ __launch_bounds__(512) void attn_fused(
    const ushort* __restrict__ qg, const ushort* __restrict__ kgl,
    const ushort* __restrict__ vg, ushort* __restrict__ og) {
  __shared__ __align__(16) ushort smem[2][7168];  // per half: Ka 2048 | Kb 1024 | Vs 4096
  const int tid = threadIdx.x;
  const int lane = tid & 63;
  const int wave = tid >> 6;          // 0..7
  const int w4 = wave & 3;            // q-wave within group
  const int kg = wave >> 2;           // key-half group
  const int l31 = lane & 31;
  const int h = lane >> 5;            // 0..1
  // XCD swizzle: lin%8 = XCD c; XCD c gets heads [8c,8c+8) x all q-tiles.
  const int lin = blockIdx.x + (blockIdx.y << 4);
  const int k8 = lin >> 3;
  const int bh = (lin & 7) * 8 + (k8 >> 4);
  const int q0 = (k8 & 15) * 128;
  const ushort* qb = qg + (size_t)bh * Sn * Dp;
  const ushort* kb = kgl + (size_t)bh * Sn * Dp + (size_t)kg * 1024 * Dp;
  const ushort* vb = vg + (size_t)bh * DhN * Sn + kg * 1024;
  ushort* KaH = &smem[kg][0];         // [64][32]
  ushort* KbH = &smem[kg][2048];      // [64][16]
  ushort* VsH = &smem[kg][3072];      // [64][64]

  // static V rows 48..63 (both halves): row 48 = 1.0 (lsum), rest 0.
  ((uint32_t*)&smem[0][6144])[tid] = (tid < 32) ? 0x3F803F80u : 0u;
  ((uint32_t*)&smem[1][6144])[tid] = (tid < 32) ? 0x3F803F80u : 0u;

  // Q B-frags (n=q=lane&31, k=dh): kc 0..2 covers dh 0..47 (pad skipped)
  s8v qf[3];
#pragma unroll
  for (int kc = 0; kc < 3; ++kc)
    qf[kc] = *(const s8v*)(qb + (size_t)(q0 + w4 * 32 + l31) * Dp + kc * 16 + h * 8);

  // DMA per half: 12 x 1KB chunks, q-wave w4 takes c = w4 + 4t -> 3 each.
  const ushort* gsrc[3];
  ushort* ldst[3];
  int gstep[3];
#pragma unroll
  for (int t = 0; t < 3; ++t) {
    const int c = w4 + 4 * t;
    if (c < 4) {            // Ka: rows 16c..16c+15, dh 0..31
      const int row = 16 * c + (lane >> 2), j = lane & 3;
      gsrc[t] = kb + (size_t)row * Dp + (j ^ ((row >> 1) & 3)) * 8;
      ldst[t] = KaH + 16 * c * 32 + lane * 8;
      gstep[t] = 64 * Dp;
    } else if (c < 6) {     // Kb: rows 32(c-4)..+31, dh 32..47
      const int row = 32 * (c - 4) + (lane >> 1), j = lane & 1;
      gsrc[t] = kb + (size_t)row * Dp + 32 + (j ^ ((row >> 2) & 1)) * 8;
      ldst[t] = KbH + 32 * (c - 4) * 16 + lane * 8;
      gstep[t] = 64 * Dp;
    } else {                // V: rows 8(c-6)..+7
      const int row = 8 * (c - 6) + (lane >> 3), j = lane & 7;
      gsrc[t] = vb + (size_t)row * Sn + (j ^ (row & 7)) * 8;
      ldst[t] = VsH + 8 * (c - 6) * 64 + lane * 8;
      gstep[t] = 64;
    }
  }

  f16v o0 = {}, o1 = {};   // O cols dh 0..31 / dh 32..63 (col 16 of o1 = lsum)

  for (int kt = 0; kt < 1024; kt += 64) {
    __syncthreads();
#pragma unroll
    for (int t = 0; t < 3; ++t) {
      gload_lds16(gsrc[t], ldst[t]);
      gsrc[t] += gstep[t];
    }
    __syncthreads();

#pragma unroll
    for (int mg = 0; mg < 2; ++mg) {        // key group: 32 keys
      const int row = 32 * mg + l31;        // key for A-frag
      const int s1 = (l31 >> 1) & 3, s2 = (l31 >> 2) & 1;
      s8v a0 = *(const s8v*)(KaH + row * 32 + ((0 | h) ^ s1) * 8);
      s8v a1 = *(const s8v*)(KaH + row * 32 + ((2 | h) ^ s1) * 8);
      s8v a2 = *(const s8v*)(KbH + row * 16 + ((h) ^ s2) * 8);
      f16v sc = {};
      __builtin_amdgcn_s_setprio(1);
      sc = MFMA32(a0, qf[0], sc);
      sc = MFMA32(a1, qf[1], sc);
      sc = MFMA32(a2, qf[2], sc);           // S^T: col=q(lane&31), row=key(reg,h)
      __builtin_amdgcn_s_setprio(0);
      float p[16];
#pragma unroll
      for (int r = 0; r < 16; ++r) p[r] = fexp2(sc[r]);

#pragma unroll
      for (int c2 = 0; c2 < 2; ++c2) {      // 16-key chunks of this group
        const int rb = 8 * c2;
        uint32_t w0 = packbf(p[rb + 0], p[rb + 1]);
        uint32_t w1 = packbf(p[rb + 2], p[rb + 3]);
        uint32_t w2 = packbf(p[rb + 4], p[rb + 5]);
        uint32_t w3 = packbf(p[rb + 6], p[rb + 7]);
        pl32swap(w0, w2);
        pl32swap(w1, w3);
        uint4 af = { w0, w1, w2, w3 };
        const s8v pa = __builtin_bit_cast(s8v, af);
        const int kcv = 2 * mg + c2;        // 16-key chunk index in 64-key tile
        const int vc = ((2 * kcv + h) ^ (l31 & 7)) * 8;
        const s8v v0 = *(const s8v*)(VsH + l31 * 64 + vc);
        const s8v v1 = *(const s8v*)(VsH + (32 + l31) * 64 + vc);
        __builtin_amdgcn_s_setprio(1);
        o0 = MFMA32(pa, v0, o0);
        o1 = MFMA32(pa, v1, o1);
        __builtin_amdgcn_s_setprio(0);
      }
    }
  }

  // ---- in-LDS combine (exact: disjoint-key partials add; v14-passing math).
  __syncthreads();
  float* scr = (float*)&smem[0][0];
  if (kg == 1) {
#pragma unroll
    for (int r = 0; r < 16; ++r) scr[r * 256 + w4 * 64 + lane] = o0[r];
  }
  __syncthreads();
  if (kg == 0) {
#pragma unroll
    for (int r = 0; r < 16; ++r) o0[r] += scr[r * 256 + w4 * 64 + lane];
  }
  __syncthreads();
  if (kg == 1) {
#pragma unroll
    for (int r = 0; r < 16; ++r) scr[r * 256 + w4 * 64 + lane] = o1[r];
  }
  __syncthreads();
  if (kg == 0) {
#pragma unroll
    for (int r = 0; r < 16; ++r) o1[r] += scr[r * 256 + w4 * 64 + lane];

    const int b = bh >> 4, hh = bh & 15;
#pragma unroll
    for (int r = 0; r < 16; ++r) {
      const int q = (r & 3) + 8 * (r >> 2) + 4 * h;
      const float lsum = __shfl(o1[r], 16 + (lane & 32), 64);  // dh48 ones row
      const float inv = 1.0f / lsum;
      const int s = q0 + w4 * 32 + q;
      const size_t base = ((size_t)(b * Sn + s)) * Dn + hh * DhN;
      og[base + l31] = f2b(o0[r] * inv);
      if (l31 < 16) og[base + 32 + l31] = f2b(o1[r] * inv);
    }
  }
}

extern "C" void kernel_launch(void* const* d_in, const int* in_sizes, int n_in,
                              void* d_out, int out_size, void* d_ws, size_t ws_size,
                              hipStream_t stream) {
  (void)in_sizes; (void)n_in; (void)out_size; (void)ws_size;
  const float* x  = (const float*)d_in[0];
  const float* Wq = (const float*)d_in[1];
  const float* bq = (const float*)d_in[2];
  const float* Wk = (const float*)d_in[3];
  const float* bk = (const float*)d_in[4];
  const float* Wv = (const float*)d_in[5];
  const float* bv = (const float*)d_in[6];
  const float* Wo = (const float*)d_in[7];
  const float* bo = (const float*)d_in[8];

  size_t off = 0;
  auto alloc = [&](size_t bytes) {
    void* p = (char*)d_ws + off;
    off += (bytes + 255) & ~(size_t)255;
    return p;
  };
  ushort* Wqkvb = (ushort*)alloc((size_t)3 * Dn * Dn * 2);
  ushort* Wob   = (ushort*)alloc((size_t)Dn * Dn * 2);
  ushort* qbuf  = (ushort*)alloc((size_t)Bn * Hn * Sn * Dp * 2);
  ushort* kbuf  = (ushort*)alloc((size_t)Bn * Hn * Sn * Dp * 2);
  ushort* vbuf  = (ushort*)alloc((size_t)Bn * Hn * DhN * Sn * 2);
  ushort* ao    = (ushort*)alloc((size_t)MS * Dn * 2);

  cvt_w<<<4 * 576, 256, 0, stream>>>(Wq, Wk, Wv, Wo, Wqkvb, Wob);

  const dim3 blk(256);
  // scale = log2(e)/sqrt(48): softmax computed in exp2 domain
  const float qscale = 0.20823510929813633f;
  gemm_qkv<<<dim3(18, MS / 128), blk, 0, stream>>>(x, Wqkvb, bq, bk, bv,
                                                   qbuf, kbuf, vbuf, qscale);

  attn_fused<<<dim3(Sn / 128, Bn * Hn), dim3(512), 0, stream>>>(qbuf, kbuf, vbuf, ao);

  gemm_out<<<dim3(6, MS / 64), blk, 0, stream>>>(ao, Wob, bo, (float*)d_out);
}

// Round 14
// 222.839 us; speedup vs baseline: 1.0451x; 1.0451x over previous
//
#include <hip/hip_runtime.h>
#include <cstdint>
#include <cstddef>

// MultiHeadAttention: B=4, S=2048, D=768, H=16, Dh=48, fp32 I/O.
// bf16 MFMA: cvt_all -> fused QKV GEMM -> in-block split-K flash-attn -> out GEMM
// v19: revert v18's fused A-cvt (reg-staging slower than gload_lds, T14 caveat
// confirmed: 228.5 -> 232.9). Back to cvt_all + DMA staging. NEW: gemm_qkv
// retiled 128x128 -> 64x128 (the transform that paid on gemm_out in r12):
// grid 1152 (4.5/CU, half-wave tail) -> 2304 = 9.0/CU zero tail; LDS 32->24KB
// (6 resident). Same k0/h accumulation order -> bit-identical numerics.
// Carried: XCD swizzle all kernels (qkv chunk=288), BK=64, gemm_out 64x128,
// in-block split-K attn + setprio (77.5us), packbf, permlane32_swap,
// dh-pad skip, xor-swizzled frags.

typedef short s8v __attribute__((ext_vector_type(8)));    // 8 x bf16 (4 VGPRs)
typedef float f4v __attribute__((ext_vector_type(4)));    // 16x16 accumulator
typedef float f16v __attribute__((ext_vector_type(16)));  // 32x32 accumulator

static constexpr int Bn = 4, Sn = 2048, Dn = 768, Hn = 16, DhN = 48, Dp = 64;
static constexpr int MS = Bn * Sn;  // 8192 rows

#define MFMA16(a, b, c) __builtin_amdgcn_mfma_f32_16x16x32_bf16((a), (b), (c), 0, 0, 0)
#define MFMA32(a, b, c) __builtin_amdgcn_mfma_f32_32x32x16_bf16((a), (b), (c), 0, 0, 0)

__device__ __forceinline__ int swz4(int r) { return (r + (r >> 2)) & 3; }

__device__ __forceinline__ ushort f2b(float f) {
  return (ushort)((__builtin_bit_cast(uint32_t, f) + 0x8000u) >> 16);
}
// pack hi16(a+0x8000), hi16(b+0x8000) via v_perm_b32 (a -> low half)
__device__ __forceinline__ uint32_t packbf(float a, float b) {
  uint32_t ua = __builtin_bit_cast(uint32_t, a) + 0x8000u;
  uint32_t ub = __builtin_bit_cast(uint32_t, b) + 0x8000u;
  return __builtin_amdgcn_perm(ub, ua, 0x07060302u);
}
// swap upper 32 lanes of a with lower 32 lanes of b (in place, both usable)
__device__ __forceinline__ void pl32swap(uint32_t& a, uint32_t& b) {
  asm("v_permlane32_swap_b32 %0, %1" : "+v"(a), "+v"(b));
}
__device__ __forceinline__ float fexp2(float x) {
  return __builtin_amdgcn_exp2f(x);
}
__device__ __forceinline__ void gload_lds16(const ushort* g, ushort* l) {
  __builtin_amdgcn_global_load_lds(
      (const __attribute__((address_space(1))) uint32_t*)g,
      (__attribute__((address_space(3))) uint32_t*)l, 16, 0, 0);
}

// One launch converts x (6144 blocks) + 4 weights (4*576 blocks) to bf16.
__global__ void cvt_all(const float* __restrict__ x,
                        const float* __restrict__ wq, const float* __restrict__ wk,
                        const float* __restrict__ wv, const float* __restrict__ wo,
                        ushort* __restrict__ xb, ushort* __restrict__ wqkv,
                        ushort* __restrict__ wob) {
  const int bid = blockIdx.x;
  const float* src;
  ushort* dst;
  int i;
  if (bid < 6144) {
    src = x; dst = xb; i = bid * 256 + threadIdx.x;
  } else {
    const int r = (bid - 6144) / 576;
    i = ((bid - 6144) % 576) * 256 + threadIdx.x;
    src = (r == 0) ? wq : (r == 1) ? wk : (r == 2) ? wv : wo;
    dst = (r < 3) ? (wqkv + (size_t)r * Dn * Dn) : wob;
  }
  float4 f = ((const float4*)src)[i];
  ushort4 o = { f2b(f.x), f2b(f.y), f2b(f.z), f2b(f.w) };
  ((ushort4*)dst)[i] = o;
}

// ---- Fused QKV GEMM (A=xb bf16 via gload_lds; B=W). Swizzled LDS. BK=64.
// v19: 64x128 tile (m halved). Grid 18x128 = 2304 blocks = 9.0/CU, zero tail
// (was 1152 = 4.5/CU). LDS 24KB -> 6 resident. acc[4][2]; same k0/h order ->
// bit-identical. XCD swizzle: nwg=2304 (%8==0), chunk=288.
__global__ __launch_bounds__(256) void gemm_qkv(
    const ushort* __restrict__ A, const ushort* __restrict__ W,
    const float* __restrict__ bq, const float* __restrict__ bk, const float* __restrict__ bv,
    ushort* __restrict__ outq, ushort* __restrict__ outk, ushort* __restrict__ outv,
    float qscale) {
  __shared__ __align__(16) ushort As[64][64];    // x rows
  __shared__ __align__(16) ushort Bs[128][64];   // W rows
  const int tid = threadIdx.x, lane = tid & 63, wave = tid >> 6;
  const int l15 = lane & 15, g = lane >> 4;
  const int lin0 = blockIdx.x + blockIdx.y * 18;        // 0..2303
  const int lin = (lin0 & 7) * 288 + (lin0 >> 3);       // XCD-chunked, bijective
  const int nx = lin % 18, my = lin / 18;
  const int m0 = my * 64, n0 = nx * 128;
  const int wqm = (wave >> 1) * 64;   // weight-dim quadrant (n: 0/64)
  const int wqx = (wave & 1) * 32;    // x-dim quadrant (m: 0/32)
  f4v acc[4][2] = {};                 // [i=wtile][j=xtile]

  // B staging: 128 rows = 4 slots/thread. A: 64 rows = 2 slots.
  const ushort* agp[2];
  const ushort* bgp[4];
  ushort* lap[2];
  ushort* lbp[4];
#pragma unroll
  for (int q = 0; q < 4; ++q) {
    const int slot = q * 256 + wave * 64 + lane;   // 0..1023
    const int r = slot >> 3, sc = slot & 7;
    const int u = ((((sc & 3) ^ swz4(r & 15)) | (sc & 4)) ^ ((r & 1) << 2)) * 8;
    bgp[q] = W + (size_t)(n0 + r) * Dn + u;
    lbp[q] = &Bs[0][0] + slot * 8;
    if (q < 2) {
      agp[q] = A + (size_t)(m0 + r) * Dn + u;
      lap[q] = &As[0][0] + slot * 8;
    }
  }
  const int fcol = (g ^ swz4(l15)) * 8;
  const int par = l15 & 1;

  for (int k0 = 0; k0 < Dn; k0 += 64) {
    __syncthreads();
#pragma unroll
    for (int q = 0; q < 4; ++q) gload_lds16(bgp[q] + k0, lbp[q]);
#pragma unroll
    for (int q = 0; q < 2; ++q) gload_lds16(agp[q] + k0, lap[q]);
    __syncthreads();
#pragma unroll
    for (int h = 0; h < 2; ++h) {
      const int fc = fcol + 32 * (h ^ par);   // holds global k-substep h
      s8v wf[4], xf[2];
#pragma unroll
      for (int i = 0; i < 4; ++i) wf[i] = *(const s8v*)&Bs[wqm + i * 16 + l15][fc];
#pragma unroll
      for (int j = 0; j < 2; ++j) xf[j] = *(const s8v*)&As[wqx + j * 16 + l15][fc];
#pragma unroll
      for (int i = 0; i < 4; ++i)
#pragma unroll
        for (int j = 0; j < 2; ++j) acc[i][j] = MFMA16(wf[i], xf[j], acc[i][j]);
    }
  }

  const int region = nx / 6;                // uniform per block
  const int nbase = n0 - region * 768;
  const float* bias = (region == 0) ? bq : (region == 1) ? bk : bv;
#pragma unroll
  for (int i = 0; i < 4; ++i) {
    const int n = nbase + wqm + i * 16 + g * 4;   // 4 consecutive n, same head
    const float4 b4 = *(const float4*)&bias[n];
    const int h = n / DhN, dh = n - h * DhN;
#pragma unroll
    for (int j = 0; j < 2; ++j) {
      const int s = m0 + wqx + j * 16 + l15;
      const int b = s >> 11, srow = s & 2047;
      const int bh = b * Hn + h;
      float v0 = acc[i][j][0] + b4.x, v1 = acc[i][j][1] + b4.y;
      float v2 = acc[i][j][2] + b4.z, v3 = acc[i][j][3] + b4.w;
      if (region == 0) { v0 *= qscale; v1 *= qscale; v2 *= qscale; v3 *= qscale; }
      if (region < 2) {
        ushort4 o = { f2b(v0), f2b(v1), f2b(v2), f2b(v3) };
        ushort* dst = region ? outk : outq;
        *(ushort4*)&dst[((size_t)bh * Sn + srow) * Dp + dh] = o;
      } else {
        outv[((size_t)bh * DhN + dh + 0) * Sn + srow] = f2b(v0);
        outv[((size_t)bh * DhN + dh + 1) * Sn + srow] = f2b(v1);
        outv[((size_t)bh * DhN + dh + 2) * Sn + srow] = f2b(v2);
        outv[((size_t)bh * DhN + dh + 3) * Sn + srow] = f2b(v3);
      }
    }
  }
}

// ---- Out projection GEMM (swapped operands, float4 stores). BK=64.
// 64x128 tile; grid 768 = 3.0 blocks/CU, zero tail. XCD swizzle chunk=96.
__global__ __launch_bounds__(256) void gemm_out(
    const ushort* __restrict__ A, const ushort* __restrict__ W,
    const float* __restrict__ bias, float* __restrict__ out) {
  __shared__ __align__(16) ushort As[64][64];
  __shared__ __align__(16) ushort Bs[128][64];
  const int tid = threadIdx.x, lane = tid & 63, wave = tid >> 6;
  const int l15 = lane & 15, g = lane >> 4;
  const int lin0 = blockIdx.x + blockIdx.y * 6;         // 0..767
  const int lin = (lin0 & 7) * 96 + (lin0 >> 3);        // XCD-chunked, bijective
  const int nx = lin % 6, my = lin / 6;
  const int m0 = my * 64, n0 = nx * 128;
  const int wqm = (wave >> 1) * 64;   // n-quadrant (0/64)
  const int wqx = (wave & 1) * 32;    // m-quadrant (0/32)
  f4v acc[4][2] = {};                 // [i=n-tile][j=m-tile]

  const ushort* agp[2];
  const ushort* bgp[4];
  ushort* lap[2];
  ushort* lbp[4];
#pragma unroll
  for (int q = 0; q < 4; ++q) {
    const int slot = q * 256 + wave * 64 + lane;   // 0..1023
    const int r = slot >> 3, sc = slot & 7;
    const int u = ((((sc & 3) ^ swz4(r & 15)) | (sc & 4)) ^ ((r & 1) << 2)) * 8;
    bgp[q] = W + (size_t)(n0 + r) * Dn + u;
    lbp[q] = &Bs[0][0] + slot * 8;
    if (q < 2) {
      agp[q] = A + (size_t)(m0 + r) * Dn + u;
      lap[q] = &As[0][0] + slot * 8;
    }
  }
  const int fcol = (g ^ swz4(l15)) * 8;
  const int par = l15 & 1;

  for (int k0 = 0; k0 < Dn; k0 += 64) {
    __syncthreads();
#pragma unroll
    for (int q = 0; q < 4; ++q) gload_lds16(bgp[q] + k0, lbp[q]);
#pragma unroll
    for (int q = 0; q < 2; ++q) gload_lds16(agp[q] + k0, lap[q]);
    __syncthreads();
#pragma unroll
    for (int h = 0; h < 2; ++h) {
      const int fc = fcol + 32 * (h ^ par);
      s8v wf[4], xf[2];
#pragma unroll
      for (int i = 0; i < 4; ++i) wf[i] = *(const s8v*)&Bs[wqm + i * 16 + l15][fc];
#pragma unroll
      for (int j = 0; j < 2; ++j) xf[j] = *(const s8v*)&As[wqx + j * 16 + l15][fc];
#pragma unroll
      for (int i = 0; i < 4; ++i)
#pragma unroll
        for (int j = 0; j < 2; ++j) acc[i][j] = MFMA16(wf[i], xf[j], acc[i][j]);
    }
  }

#pragma unroll
  for (int i = 0; i < 4; ++i) {
    const int n = n0 + wqm + i * 16 + g * 4;
    const float4 b4 = *(const float4*)&bias[n];
#pragma unroll
    for (int j = 0; j < 2; ++j) {
      const int s = m0 + wqx + j * 16 + l15;
      float4 o4 = { acc[i][j][0] + b4.x, acc[i][j][1] + b4.y,
                    acc[i][j][2] + b4.z, acc[i][j][3] + b4.w };
      *(float4*)&out[(size_t)s * Dn + n] = o4;
    }
  }
}

// ---- In-block split-K flash attention (v17, passing, verbatim). grid (16, 64),
// block 512 (8 waves = 2 key-groups x 4 q-waves of 32 q each). Group g: keys
// [1024g, 1024g+1024), 16 x 64-key tiles in its own LDS half (14KB).
// Epilogue: group 1 -> LDS scratch (transposed, conflict-free), group 0 adds
// + normalizes (lsum = dh48 ones-row col). setprio around MFMA clusters.
__global__ __launch_bounds__(512) void attn_fused(
    const ushort* __restrict__ qg, const ushort* __restrict__ kgl,
    const ushort* __restrict__ vg, ushort* __restrict__ og) {
  __shared__ __align__(16) ushort smem[2][7168];  // per half: Ka 2048 | Kb 1024 | Vs 4096
  const int tid = threadIdx.x;
  const int lane = tid & 63;
  const int wave = tid >> 6;          // 0..7
  const int w4 = wave & 3;            // q-wave within group
  const int kg = wave >> 2;           // key-half group
  const int l31 = lane & 31;
  const int h = lane >> 5;            // 0..1
  // XCD swizzle: lin%8 = XCD c; XCD c gets heads [8c,8c+8) x all q-tiles.
  const int lin = blockIdx.x + (blockIdx.y << 4);
  const int k8 = lin >> 3;
  const int bh = (lin & 7) * 8 + (k8 >> 4);
  const int q0 = (k8 & 15) * 128;
  const ushort* qb = qg + (size_t)bh * Sn * Dp;
  const ushort* kb = kgl + (size_t)bh * Sn * Dp + (size_t)kg * 1024 * Dp;
  const ushort* vb = vg + (size_t)bh * DhN * Sn + kg * 1024;
  ushort* KaH = &smem[kg][0];         // [64][32]
  ushort* KbH = &smem[kg][2048];      // [64][16]
  ushort* VsH = &smem[kg][3072];      // [64][64]

  // static V rows 48..63 (both halves): row 48 = 1.0 (lsum), rest 0.
  ((uint32_t*)&smem[0][6144])[tid] = (tid < 32) ? 0x3F803F80u : 0u;
  ((uint32_t*)&smem[1][6144])[tid] = (tid < 32) ? 0x3F803F80u : 0u;

  // Q B-frags (n=q=lane&31, k=dh): kc 0..2 covers dh 0..47 (pad skipped)
  s8v qf[3];
#pragma unroll
  for (int kc = 0; kc < 3; ++kc)
    qf[kc] = *(const s8v*)(qb + (size_t)(q0 + w4 * 32 + l31) * Dp + kc * 16 + h * 8);

  // DMA per half: 12 x 1KB chunks, q-wave w4 takes c = w4 + 4t -> 3 each.
  const ushort* gsrc[3];
  ushort* ldst[3];
  int gstep[3];
#pragma unroll
  for (int t = 0; t < 3; ++t) {
    const int c = w4 + 4 * t;
    if (c < 4) {            // Ka: rows 16c..16c+15, dh 0..31
      const int row = 16 * c + (lane >> 2), j = lane & 3;
      gsrc[t] = kb + (size_t)row * Dp + (j ^ ((row >> 1) & 3)) * 8;
      ldst[t] = KaH + 16 * c * 32 + lane * 8;
      gstep[t] = 64 * Dp;
    } else if (c < 6) {     // Kb: rows 32(c-4)..+31, dh 32..47
      const int row = 32 * (c - 4) + (lane >> 1), j = lane & 1;
      gsrc[t] = kb + (size_t)row * Dp + 32 + (j ^ ((row >> 2) & 1)) * 8;
      ldst[t] = KbH + 32 * (c - 4) * 16 + lane * 8;
      gstep[t] = 64 * Dp;
    } else {                // V: rows 8(c-6)..+7
      const int row = 8 * (c - 6) + (lane >> 3), j = lane & 7;
      gsrc[t] = vb + (size_t)row * Sn + (j ^ (row & 7)) * 8;
      ldst[t] = VsH + 8 * (c - 6) * 64 + lane * 8;
      gstep[t] = 64;
    }
  }

  f16v o0 = {}, o1 = {};   // O cols dh 0..31 / dh 32..63 (col 16 of o1 = lsum)

  for (int kt = 0; kt < 1024; kt += 64) {
    __syncthreads();
#pragma unroll
    for (int t = 0; t < 3; ++t) {
      gload_lds16(gsrc[t], ldst[t]);
      gsrc[t] += gstep[t];
    }
    __syncthreads();

#pragma unroll
    for (int mg = 0; mg < 2; ++mg) {        // key group: 32 keys
      const int row = 32 * mg + l31;        // key for A-frag
      const int s1 = (l31 >> 1) & 3, s2 = (l31 >> 2) & 1;
      s8v a0 = *(const s8v*)(KaH + row * 32 + ((0 | h) ^ s1) * 8);
      s8v a1 = *(const s8v*)(KaH + row * 32 + ((2 | h) ^ s1) * 8);
      s8v a2 = *(const s8v*)(KbH + row * 16 + ((h) ^ s2) * 8);
      f16v sc = {};
      __builtin_amdgcn_s_setprio(1);
      sc = MFMA32(a0, qf[0], sc);
      sc = MFMA32(a1, qf[1], sc);
      sc = MFMA32(a2, qf[2], sc);           // S^T: col=q(lane&31), row=key(reg,h)
      __builtin_amdgcn_s_setprio(0);
      float p[16];
#pragma unroll
      for (int r = 0; r < 16; ++r) p[r] = fexp2(sc[r]);

#pragma unroll
      for (int c2 = 0; c2 < 2; ++c2) {      // 16-key chunks of this group
        const int rb = 8 * c2;
        uint32_t w0 = packbf(p[rb + 0], p[rb + 1]);
        uint32_t w1 = packbf(p[rb + 2], p[rb + 3]);
        uint32_t w2 = packbf(p[rb + 4], p[rb + 5]);
        uint32_t w3 = packbf(p[rb + 6], p[rb + 7]);
        pl32swap(w0, w2);
        pl32swap(w1, w3);
        uint4 af = { w0, w1, w2, w3 };
        const s8v pa = __builtin_bit_cast(s8v, af);
        const int kcv = 2 * mg + c2;        // 16-key chunk index in 64-key tile
        const int vc = ((2 * kcv + h) ^ (l31 & 7)) * 8;
        const s8v v0 = *(const s8v*)(VsH + l31 * 64 + vc);
        const s8v v1 = *(const s8v*)(VsH + (32 + l31) * 64 + vc);
        __builtin_amdgcn_s_setprio(1);
        o0 = MFMA32(pa, v0, o0);
        o1 = MFMA32(pa, v1, o1);
        __builtin_amdgcn_s_setprio(0);
      }
    }
  }

  // ---- in-LDS combine (exact: disjoint-key partials add; v14-passing math).
  __syncthreads();
  float* scr = (float*)&smem[0][0];
  if (kg == 1) {
#pragma unroll
    for (int r = 0; r < 16; ++r) scr[r * 256 + w4 * 64 + lane] = o0[r];
  }
  __syncthreads();
  if (kg == 0) {
#pragma unroll
    for (int r = 0; r < 16; ++r) o0[r] += scr[r * 256 + w4 * 64 + lane];
  }
  __syncthreads();
  if (kg == 1) {
#pragma unroll
    for (int r = 0; r < 16; ++r) scr[r * 256 + w4 * 64 + lane] = o1[r];
  }
  __syncthreads();
  if (kg == 0) {
#pragma unroll
    for (int r = 0; r < 16; ++r) o1[r] += scr[r * 256 + w4 * 64 + lane];

    const int b = bh >> 4, hh = bh & 15;
#pragma unroll
    for (int r = 0; r < 16; ++r) {
      const int q = (r & 3) + 8 * (r >> 2) + 4 * h;
      const float lsum = __shfl(o1[r], 16 + (lane & 32), 64);  // dh48 ones row
      const float inv = 1.0f / lsum;
      const int s = q0 + w4 * 32 + q;
      const size_t base = ((size_t)(b * Sn + s)) * Dn + hh * DhN;
      og[base + l31] = f2b(o0[r] * inv);
      if (l31 < 16) og[base + 32 + l31] = f2b(o1[r] * inv);
    }
  }
}

extern "C" void kernel_launch(void* const* d_in, const int* in_sizes, int n_in,
                              void* d_out, int out_size, void* d_ws, size_t ws_size,
                              hipStream_t stream) {
  (void)in_sizes; (void)n_in; (void)out_size; (void)ws_size;
  const float* x  = (const float*)d_in[0];
  const float* Wq = (const float*)d_in[1];
  const float* bq = (const float*)d_in[2];
  const float* Wk = (const float*)d_in[3];
  const float* bk = (const float*)d_in[4];
  const float* Wv = (const float*)d_in[5];
  const float* bv = (const float*)d_in[6];
  const float* Wo = (const float*)d_in[7];
  const float* bo = (const float*)d_in[8];

  size_t off = 0;
  auto alloc = [&](size_t bytes) {
    void* p = (char*)d_ws + off;
    off += (bytes + 255) & ~(size_t)255;
    return p;
  };
  ushort* xb    = (ushort*)alloc((size_t)MS * Dn * 2);
  ushort* Wqkvb = (ushort*)alloc((size_t)3 * Dn * Dn * 2);
  ushort* Wob   = (ushort*)alloc((size_t)Dn * Dn * 2);
  ushort* qbuf  = (ushort*)alloc((size_t)Bn * Hn * Sn * Dp * 2);
  ushort* kbuf  = (ushort*)alloc((size_t)Bn * Hn * Sn * Dp * 2);
  ushort* vbuf  = (ushort*)alloc((size_t)Bn * Hn * DhN * Sn * 2);
  ushort* ao    = (ushort*)alloc((size_t)MS * Dn * 2);

  cvt_all<<<6144 + 4 * 576, 256, 0, stream>>>(x, Wq, Wk, Wv, Wo, xb, Wqkvb, Wob);

  const dim3 blk(256);
  // scale = log2(e)/sqrt(48): softmax computed in exp2 domain
  const float qscale = 0.20823510929813633f;
  gemm_qkv<<<dim3(18, MS / 64), blk, 0, stream>>>(xb, Wqkvb, bq, bk, bv,
                                                  qbuf, kbuf, vbuf, qscale);

  attn_fused<<<dim3(Sn / 128, Bn * Hn), dim3(512), 0, stream>>>(qbuf, kbuf, vbuf, ao);

  gemm_out<<<dim3(6, MS / 64), blk, 0, stream>>>(ao, Wob, bo, (float*)d_out);
}